// Round 12
// baseline (207.687 us; speedup 1.0000x reference)
//
#include <hip/hip_runtime.h>
#include <hip/hip_bf16.h>

#define N_NODES 10000
#define N_EDGES 640000
#define CH 128
#define NB 64                // histogram/scatter blocks
#define EPB (N_EDGES / NB)   // 10000 edges per block
#define NCHUNK 40            // ceil(N_NODES/256) scan chunks
#define NPAD 10240           // NCHUNK*256

typedef float f32x4 __attribute__((ext_vector_type(4)));

// ---------------------------------------------------------------------------
// K1: FUSED. Blocks [0,NB): per-block LDS DUAL histogram (count + weighted
// degree, 80 KB) + chunk count-partials. Blocks [NB, NB+157): gemm1 = x@W1^T.
// Block NB+157: conv/fc weight fold.  (round-4 proven, verbatim)
__global__ __launch_bounds__(256) void fused_hist_gemm(const int* __restrict__ ei,
        const float* __restrict__ ew,
        const float* __restrict__ x, const float* __restrict__ W1,
        int* __restrict__ hist, float* __restrict__ dhist, int* __restrict__ pcs,
        float* __restrict__ out,
        const float* __restrict__ conv_w, const float* __restrict__ conv_b,
        const float* __restrict__ fc_w, const float* __restrict__ fc_b,
        float* __restrict__ vbuf, float* __restrict__ c0) {
    __shared__ __align__(16) char smem[NPAD * 8];    // 80 KB union
    int t = threadIdx.x;
    int bid = blockIdx.x;
    if (bid < NB) {
        int* h = (int*)smem;                         // 40 KB counts
        float* hf = (float*)(smem + NPAD * 4);       // 40 KB weighted degree
        for (int i = t; i < 2 * NPAD; i += 256) ((int*)smem)[i] = 0;
        __syncthreads();
        int e0 = bid * EPB;
        for (int i = t; i < EPB; i += 256) {
            int e = e0 + i;
            int c = ei[N_EDGES + e];
            atomicAdd(&h[c], 1);                     // LDS atomics
            atomicAdd(&hf[c], ew[e]);
        }
        __syncthreads();
        for (int i = t; i < N_NODES; i += 256) {
            hist[bid * N_NODES + i] = h[i];
            dhist[bid * N_NODES + i] = hf[i];
        }
        int lane = t & 63, wave = t >> 6;
        for (int cch = wave; cch < NCHUNK; cch += 4) {
            int s = h[cch * 256 + lane] + h[cch * 256 + lane + 64]
                  + h[cch * 256 + lane + 128] + h[cch * 256 + lane + 192];
            #pragma unroll
            for (int off = 32; off > 0; off >>= 1) s += __shfl_down(s, off, 64);
            if (lane == 0) pcs[cch * NB + bid] = s;  // chunk-major layout
        }
        return;
    }
    if (bid == NB + (N_NODES + 63) / 64) {
        for (int i = t; i <= 384; i += 256) {
            if (i < 384) {
                float s = 0.0f;
                for (int o = 0; o < CH; ++o) s += fc_w[o] * conv_w[o * 384 + i];
                vbuf[i] = s;
            } else {
                float s = fc_b[0];
                for (int o = 0; o < CH; ++o) s += fc_w[o] * conv_b[o];
                *c0 = s;
            }
        }
        return;
    }
    // ---- gemm path: out[m][o] = sum_k x[m][k] * W1[o][k] ----
    float (*As)[68]  = (float(*)[68])smem;
    float (*Ws)[132] = (float(*)[132])(smem + 32 * 68 * sizeof(float));
    int tx = t & 31;
    int ty = t >> 5;
    int row0 = (bid - NB) * 64;
    float acc[8][4] = {};
    for (int k0 = 0; k0 < 128; k0 += 32) {
        #pragma unroll
        for (int i = 0; i < 8; ++i) {
            int idx = t + i * 256;
            int r = idx >> 5, k = idx & 31;
            int gr = row0 + r;
            As[k][r] = (gr < N_NODES) ? x[gr * CH + k0 + k] : 0.0f;
        }
        #pragma unroll
        for (int i = 0; i < 16; ++i) {
            int idx = t + i * 256;
            int o = idx >> 5, k = idx & 31;
            Ws[k][o] = W1[o * CH + k0 + k];
        }
        __syncthreads();
        #pragma unroll
        for (int kk = 0; kk < 32; ++kk) {
            float a[8], w[4];
            #pragma unroll
            for (int j = 0; j < 8; ++j) a[j] = As[kk][ty * 8 + j];
            #pragma unroll
            for (int c = 0; c < 4; ++c) w[c] = Ws[kk][tx * 4 + c];
            #pragma unroll
            for (int j = 0; j < 8; ++j)
                #pragma unroll
                for (int c = 0; c < 4; ++c)
                    acc[j][c] += a[j] * w[c];
        }
        __syncthreads();
    }
    #pragma unroll
    for (int j = 0; j < 8; ++j) {
        int gr = row0 + ty * 8 + j;
        if (gr < N_NODES) {
            float4 v = make_float4(acc[j][0], acc[j][1], acc[j][2], acc[j][3]);
            *reinterpret_cast<float4*>(&out[gr * CH + tx * 4]) = v;
        }
    }
}

// ---------------------------------------------------------------------------
// K2: per-node totals + dinv + global exclusive prefix + cursor conversion.
// (round-4 proven, verbatim)
__global__ __launch_bounds__(256) void bofs_kernel(int* __restrict__ hist,
        const float* __restrict__ dhist, const int* __restrict__ pcs,
        int* __restrict__ tot, int* __restrict__ offs, float* __restrict__ dinv) {
    __shared__ int wred[4];
    __shared__ int wsum[4];
    __shared__ int base_sh;
    int blk = blockIdx.x, t = threadIdx.x;
    int lane = t & 63, wave = t >> 6;
    int bsum = 0;
    for (int i = t; i < blk * NB; i += 256) bsum += pcs[i];
    #pragma unroll
    for (int off = 32; off > 0; off >>= 1) bsum += __shfl_down(bsum, off, 64);
    if (lane == 0) wred[wave] = bsum;
    __syncthreads();
    if (t == 0) base_sh = wred[0] + wred[1] + wred[2] + wred[3];
    int n = blk * 256 + t;
    int v = 0;
    if (n < N_NODES) {
        float dsum = 0.0f;
        #pragma unroll 8
        for (int b = 0; b < NB; ++b) {
            v += hist[b * N_NODES + n];
            dsum += dhist[b * N_NODES + n];
        }
        tot[n] = v;
        dinv[n] = rsqrtf(dsum + 1.0f);            // +1 = self-loop weight
    }
    int s = v;
    #pragma unroll
    for (int off = 1; off < 64; off <<= 1) {
        int u = __shfl_up(s, off, 64);
        if (lane >= off) s += u;
    }
    if (lane == 63) wsum[wave] = s;
    __syncthreads();
    int wbase = 0;
    for (int i = 0; i < wave; ++i) wbase += wsum[i];
    if (n < N_NODES) {
        int run = base_sh + wbase + s - v;        // global exclusive prefix
        offs[n] = run;
        for (int b = 0; b < NB; ++b) {
            int h = hist[b * N_NODES + n];
            hist[b * N_NODES + n] = run;          // column -> start cursor
            run += h;
        }
    }
}

// ---------------------------------------------------------------------------
// K3: scatter edges into CSR order via LDS cursors; records carry the fully
// NORMALIZED value dinv[r]*w*dinv[c].  (round-4 proven, verbatim)
__global__ __launch_bounds__(256) void scatter_kernel(const int* __restrict__ ei,
        const float* __restrict__ ew, const float* __restrict__ dinv,
        const int* __restrict__ bofs, int2* __restrict__ erec) {
    __shared__ int cur[N_NODES];                 // 40 KB
    __shared__ float di[N_NODES];                // 40 KB
    int b = blockIdx.x, t = threadIdx.x;
    for (int i = t; i < N_NODES; i += 256) {
        cur[i] = bofs[b * N_NODES + i];
        di[i] = dinv[i];
    }
    __syncthreads();
    int e0 = b * EPB;
    for (int i = t; i < EPB; i += 256) {
        int e = e0 + i;
        int r = ei[e];
        int c = ei[N_EDGES + e];
        float v = di[r] * ew[e] * di[c];
        int p = atomicAdd(&cur[c], 1);           // LDS atomic
        erec[p] = make_int2(r, __float_as_int(v));
    }
}

// ---------------------------------------------------------------------------
// All waits INTERNAL to a single asm block (round-11 lesson: in-flight load
// destinations must never be visible to the register allocator across
// statement boundaries — it may insert copies that read stale registers).
// 16-wide: one full-latency exposure per 16 edges instead of per 8.
#define GATHER16_ASM() \
      asm volatile( \
        "global_load_dwordx4 %0, %16, off\n\t"  \
        "global_load_dwordx4 %1, %17, off\n\t"  \
        "global_load_dwordx4 %2, %18, off\n\t"  \
        "global_load_dwordx4 %3, %19, off\n\t"  \
        "global_load_dwordx4 %4, %20, off\n\t"  \
        "global_load_dwordx4 %5, %21, off\n\t"  \
        "global_load_dwordx4 %6, %22, off\n\t"  \
        "global_load_dwordx4 %7, %23, off\n\t"  \
        "global_load_dwordx4 %8, %24, off\n\t"  \
        "global_load_dwordx4 %9, %25, off\n\t"  \
        "global_load_dwordx4 %10, %26, off\n\t" \
        "global_load_dwordx4 %11, %27, off\n\t" \
        "global_load_dwordx4 %12, %28, off\n\t" \
        "global_load_dwordx4 %13, %29, off\n\t" \
        "global_load_dwordx4 %14, %30, off\n\t" \
        "global_load_dwordx4 %15, %31, off\n\t" \
        "s_waitcnt vmcnt(0)"                    \
        : "=&v"(f0), "=&v"(f1), "=&v"(f2), "=&v"(f3),     \
          "=&v"(f4), "=&v"(f5), "=&v"(f6), "=&v"(f7),     \
          "=&v"(f8), "=&v"(f9), "=&v"(f10), "=&v"(f11),   \
          "=&v"(f12), "=&v"(f13), "=&v"(f14), "=&v"(f15)  \
        : "v"(p0), "v"(p1), "v"(p2), "v"(p3),   \
          "v"(p4), "v"(p5), "v"(p6), "v"(p7),   \
          "v"(p8), "v"(p9), "v"(p10), "v"(p11), \
          "v"(p12), "v"(p13), "v"(p14), "v"(p15))

#define GATHER8_ASM(F0,F1,F2,F3,F4,F5,F6,F7, P0,P1,P2,P3,P4,P5,P6,P7)        \
    asm volatile(                                                            \
        "global_load_dwordx4 %0, %8, off\n\t"                                \
        "global_load_dwordx4 %1, %9, off\n\t"                                \
        "global_load_dwordx4 %2, %10, off\n\t"                               \
        "global_load_dwordx4 %3, %11, off\n\t"                               \
        "global_load_dwordx4 %4, %12, off\n\t"                               \
        "global_load_dwordx4 %5, %13, off\n\t"                               \
        "global_load_dwordx4 %6, %14, off\n\t"                               \
        "global_load_dwordx4 %7, %15, off\n\t"                               \
        "s_waitcnt vmcnt(0)"                                                 \
        : "=&v"(F0), "=&v"(F1), "=&v"(F2), "=&v"(F3),                        \
          "=&v"(F4), "=&v"(F5), "=&v"(F6), "=&v"(F7)                         \
        : "v"(P0), "v"(P1), "v"(P2), "v"(P3),                                \
          "v"(P4), "v"(P5), "v"(P6), "v"(P7))

// Shared edge-sweep body: records staged in LDS; 16-wide asm batches, then
// 8-wide, then scalar tail. Accumulation order identical to round 10.
#define EDGE_SWEEP() \
    int i = 0; \
    for (; i + 16 <= ns; i += 16) { \
        int2 r[16]; \
        _Pragma("unroll") \
        for (int j = 0; j < 16; ++j) r[j] = lrec[g][i + j]; \
        const f32x4 *p0  = xw + ((size_t)r[0].x  * 32 + l); \
        const f32x4 *p1  = xw + ((size_t)r[1].x  * 32 + l); \
        const f32x4 *p2  = xw + ((size_t)r[2].x  * 32 + l); \
        const f32x4 *p3  = xw + ((size_t)r[3].x  * 32 + l); \
        const f32x4 *p4  = xw + ((size_t)r[4].x  * 32 + l); \
        const f32x4 *p5  = xw + ((size_t)r[5].x  * 32 + l); \
        const f32x4 *p6  = xw + ((size_t)r[6].x  * 32 + l); \
        const f32x4 *p7  = xw + ((size_t)r[7].x  * 32 + l); \
        const f32x4 *p8  = xw + ((size_t)r[8].x  * 32 + l); \
        const f32x4 *p9  = xw + ((size_t)r[9].x  * 32 + l); \
        const f32x4 *p10 = xw + ((size_t)r[10].x * 32 + l); \
        const f32x4 *p11 = xw + ((size_t)r[11].x * 32 + l); \
        const f32x4 *p12 = xw + ((size_t)r[12].x * 32 + l); \
        const f32x4 *p13 = xw + ((size_t)r[13].x * 32 + l); \
        const f32x4 *p14 = xw + ((size_t)r[14].x * 32 + l); \
        const f32x4 *p15 = xw + ((size_t)r[15].x * 32 + l); \
        f32x4 f0, f1, f2, f3, f4, f5, f6, f7; \
        f32x4 f8, f9, f10, f11, f12, f13, f14, f15; \
        GATHER16_ASM(); \
        acc += __int_as_float(r[0].y)  * f0;  acc += __int_as_float(r[1].y)  * f1; \
        acc += __int_as_float(r[2].y)  * f2;  acc += __int_as_float(r[3].y)  * f3; \
        acc += __int_as_float(r[4].y)  * f4;  acc += __int_as_float(r[5].y)  * f5; \
        acc += __int_as_float(r[6].y)  * f6;  acc += __int_as_float(r[7].y)  * f7; \
        acc += __int_as_float(r[8].y)  * f8;  acc += __int_as_float(r[9].y)  * f9; \
        acc += __int_as_float(r[10].y) * f10; acc += __int_as_float(r[11].y) * f11; \
        acc += __int_as_float(r[12].y) * f12; acc += __int_as_float(r[13].y) * f13; \
        acc += __int_as_float(r[14].y) * f14; acc += __int_as_float(r[15].y) * f15; \
    } \
    for (; i + 8 <= ns; i += 8) { \
        int2 r0 = lrec[g][i+0], r1 = lrec[g][i+1], r2 = lrec[g][i+2], r3 = lrec[g][i+3]; \
        int2 r4 = lrec[g][i+4], r5 = lrec[g][i+5], r6 = lrec[g][i+6], r7 = lrec[g][i+7]; \
        const f32x4 *p0 = xw + ((size_t)r0.x * 32 + l), *p1 = xw + ((size_t)r1.x * 32 + l); \
        const f32x4 *p2 = xw + ((size_t)r2.x * 32 + l), *p3 = xw + ((size_t)r3.x * 32 + l); \
        const f32x4 *p4 = xw + ((size_t)r4.x * 32 + l), *p5 = xw + ((size_t)r5.x * 32 + l); \
        const f32x4 *p6 = xw + ((size_t)r6.x * 32 + l), *p7 = xw + ((size_t)r7.x * 32 + l); \
        f32x4 f0, f1, f2, f3, f4, f5, f6, f7; \
        GATHER8_ASM(f0, f1, f2, f3, f4, f5, f6, f7, p0, p1, p2, p3, p4, p5, p6, p7); \
        acc += __int_as_float(r0.y) * f0; \
        acc += __int_as_float(r1.y) * f1; \
        acc += __int_as_float(r2.y) * f2; \
        acc += __int_as_float(r3.y) * f3; \
        acc += __int_as_float(r4.y) * f4; \
        acc += __int_as_float(r5.y) * f5; \
        acc += __int_as_float(r6.y) * f6; \
        acc += __int_as_float(r7.y) * f7; \
    } \
    for (; i < num; ++i) { \
        int2 r = (i < ns) ? lrec[g][i] : erec[start + i]; \
        f32x4 f = xw[(size_t)r.x * 32 + l]; \
        acc += __int_as_float(r.y) * f; \
    }

// ---------------------------------------------------------------------------
// K4: FUSED agg1 + gemm2 with 16-wide asm gather batches.
__global__ __launch_bounds__(256) void agg_gemm_kernel(const f32x4* __restrict__ xw,
        const int2* __restrict__ erec, const int* __restrict__ offs,
        const int* __restrict__ cnt, const float* __restrict__ dinv,
        const float* __restrict__ bias, const float* __restrict__ W2,
        float* __restrict__ out) {
    __shared__ float hs[8][128];                 // 4 KB relu'd h1 rows
    __shared__ int2 lrec[8][128];                // 8 KB staged records
    int l = threadIdx.x & 31;                    // channel quad
    int g = threadIdx.x >> 5;                    // node group 0..7
    int n = blockIdx.x * 8 + g;
    int start = offs[n];
    int num = cnt[n];
    int ns = num <= 128 ? num : 128;             // deg>128: astronomically rare
    for (int i = l; i < ns; i += 32)             // coalesced 256 B/group/iter
        lrec[g][i] = erec[start + i];            // same-wave producer/consumer
    float d = dinv[n];
    float dd = d * d;
    f32x4 self = xw[(size_t)n * 32 + l];
    f32x4 acc = dd * self;
    EDGE_SWEEP()
    const f32x4 bb = ((const f32x4*)bias)[l];
    f32x4 h;
    h.x = fmaxf(acc.x + bb.x, 0.0f);
    h.y = fmaxf(acc.y + bb.y, 0.0f);
    h.z = fmaxf(acc.z + bb.z, 0.0f);
    h.w = fmaxf(acc.w + bb.w, 0.0f);
    *reinterpret_cast<f32x4*>(&hs[g][4 * l]) = h;
    __syncthreads();
    // ---- mini-GEMM: thread = (output channel o, row-group rg of 4 rows) ----
    int o = threadIdx.x & 127;
    int rg = threadIdx.x >> 7;                   // 0: rows 0-3, 1: rows 4-7
    const float4* w4p = reinterpret_cast<const float4*>(&W2[o * CH]);
    const float4* h0p = reinterpret_cast<const float4*>(&hs[rg * 4 + 0][0]);
    const float4* h1p = reinterpret_cast<const float4*>(&hs[rg * 4 + 1][0]);
    const float4* h2p = reinterpret_cast<const float4*>(&hs[rg * 4 + 2][0]);
    const float4* h3p = reinterpret_cast<const float4*>(&hs[rg * 4 + 3][0]);
    float a0 = 0.0f, a1 = 0.0f, a2 = 0.0f, a3 = 0.0f;
    #pragma unroll 8
    for (int k4 = 0; k4 < 32; ++k4) {
        float4 w = w4p[k4];                      // L2-hot W2 row
        float4 h0 = h0p[k4], h1 = h1p[k4], h2 = h2p[k4], h3 = h3p[k4];
        a0 += w.x * h0.x + w.y * h0.y + w.z * h0.z + w.w * h0.w;
        a1 += w.x * h1.x + w.y * h1.y + w.z * h1.z + w.w * h1.w;
        a2 += w.x * h2.x + w.y * h2.y + w.z * h2.z + w.w * h2.w;
        a3 += w.x * h3.x + w.y * h3.y + w.z * h3.z + w.w * h3.w;
    }
    int nb2 = blockIdx.x * 8 + rg * 4;
    out[(nb2 + 0) * CH + o] = a0;
    out[(nb2 + 1) * CH + o] = a1;
    out[(nb2 + 2) * CH + o] = a2;
    out[(nb2 + 3) * CH + o] = a3;
}

// ---------------------------------------------------------------------------
// K5: agg layer 2 — same 16-wide inner loop.
__global__ __launch_bounds__(256) void agg_kernel(const f32x4* __restrict__ xw,
        const int2* __restrict__ erec, const int* __restrict__ offs,
        const int* __restrict__ cnt, const float* __restrict__ dinv,
        const float* __restrict__ bias, f32x4* __restrict__ out4) {
    __shared__ int2 lrec[8][128];                // 8 KB staged records
    int l = threadIdx.x & 31;
    int g = threadIdx.x >> 5;
    int n = blockIdx.x * 8 + g;
    int start = offs[n];
    int num = cnt[n];
    int ns = num <= 128 ? num : 128;
    for (int i = l; i < ns; i += 32)
        lrec[g][i] = erec[start + i];
    float d = dinv[n];
    float dd = d * d;
    f32x4 self = xw[(size_t)n * 32 + l];
    f32x4 acc = dd * self;
    EDGE_SWEEP()
    const f32x4 bb = ((const f32x4*)bias)[l];
    f32x4 h;
    h.x = fmaxf(acc.x + bb.x, 0.0f);
    h.y = fmaxf(acc.y + bb.y, 0.0f);
    h.z = fmaxf(acc.z + bb.z, 0.0f);
    h.w = fmaxf(acc.w + bb.w, 0.0f);
    out4[(size_t)n * 32 + l] = h;
}

// ---------------------------------------------------------------------------
// K6: fused temporal conv + fc: one wave per node, lane handles ch l and l+64.
__global__ __launch_bounds__(256) void convfc_kernel(const float* __restrict__ h,
        const float* __restrict__ v, const float* __restrict__ c0,
        float* __restrict__ out, int N) {
    int n = blockIdx.x * 4 + (threadIdx.x >> 6);
    int l = threadIdx.x & 63;
    if (n >= N) return;
    const float* hn = h + n * CH;
    float v0a = v[l * 3 + 0],        v1a = v[l * 3 + 1],        v2a = v[l * 3 + 2];
    float v0b = v[(l + 64) * 3 + 0], v1b = v[(l + 64) * 3 + 1], v2b = v[(l + 64) * 3 + 2];
    float p = hn[l] * v1a + hn[l + 64] * v1b;
    if (n > 0)     p += hn[l - CH] * v0a + hn[l + 64 - CH] * v0b;
    if (n < N - 1) p += hn[l + CH] * v2a + hn[l + 64 + CH] * v2b;
    #pragma unroll
    for (int off = 32; off > 0; off >>= 1) p += __shfl_down(p, off, 64);
    if (l == 0) out[n] = p + *c0;
}

// ---------------------------------------------------------------------------
extern "C" void kernel_launch(void* const* d_in, const int* in_sizes, int n_in,
                              void* d_out, int out_size, void* d_ws, size_t ws_size,
                              hipStream_t stream) {
    const float* x       = (const float*)d_in[0];
    const int*   ei      = (const int*)d_in[1];
    const float* ew      = (const float*)d_in[2];
    const float* W1      = (const float*)d_in[3];
    const float* b1      = (const float*)d_in[4];
    const float* W2      = (const float*)d_in[5];
    const float* b2      = (const float*)d_in[6];
    const float* conv_w  = (const float*)d_in[7];
    const float* conv_b  = (const float*)d_in[8];
    const float* fc_w    = (const float*)d_in[9];
    const float* fc_b    = (const float*)d_in[10];
    float* out = (float*)d_out;

    float* bufA   = (float*)d_ws;                   // 1,280,000 f (xw1, later h2)
    float* bufB   = bufA + N_NODES * CH;            // 1,280,000 f (xw2)
    int2*  erec   = (int2*)(bufB + N_NODES * CH);   // 640,000 x 8B
    int*   hist   = (int*)(erec + N_EDGES);         // NB*10,000 i
    float* dhist  = (float*)(hist + NB * N_NODES);  // NB*10,000 f
    int*   pcs    = (int*)(dhist + NB * N_NODES);   // NCHUNK*NB i
    int*   tot    = pcs + NCHUNK * NB;              // 10,000 i
    int*   offs   = tot + N_NODES;                  // 10,000 i
    float* dinv   = (float*)(offs + N_NODES);       // 10,000 f
    float* vbuf   = dinv + N_NODES;                 // 384 f
    float* c0     = vbuf + 384;                     // 1 f

    const int gemm_grid = (N_NODES + 63) / 64;      // 157

    // K1: dual-hist (64) + gemm1 (157) + weight-fold (1), all data-independent
    fused_hist_gemm<<<NB + gemm_grid + 1, 256, 0, stream>>>(ei, ew, x, W1,
            hist, dhist, pcs, bufA, conv_w, conv_b, fc_w, fc_b, vbuf, c0);
    // K2: totals + dinv + prefix + cursor conversion
    bofs_kernel<<<NCHUNK, 256, 0, stream>>>(hist, dhist, pcs, tot, offs, dinv);
    // K3: normalized CSR scatter
    scatter_kernel<<<NB, 256, 0, stream>>>(ei, ew, dinv, hist, erec);
    // K4: agg1 + gemm2 fused (16-wide asm gathers): bufA -> bufB
    agg_gemm_kernel<<<N_NODES / 8, 256, 0, stream>>>((const f32x4*)bufA, erec, offs,
            tot, dinv, b1, W2, bufB);
    // K5: agg layer 2 (16-wide asm gathers): bufB -> bufA
    agg_kernel<<<N_NODES / 8, 256, 0, stream>>>((const f32x4*)bufB, erec, offs, tot,
                                                dinv, b2, (f32x4*)bufA);
    // K6: fused temporal conv + fc
    convfc_kernel<<<(N_NODES + 3) / 4, 256, 0, stream>>>(bufA, vbuf, c0, out, N_NODES);
}

// Round 13
// 190.739 us; speedup vs baseline: 1.0889x; 1.0889x over previous
//
#include <hip/hip_runtime.h>
#include <hip/hip_bf16.h>

#define N_NODES 10000
#define N_EDGES 640000
#define CH 128
#define NB 64                // histogram/scatter blocks
#define EPB (N_EDGES / NB)   // 10000 edges per block
#define NCHUNK 40            // ceil(N_NODES/256) scan chunks
#define NPAD 10240           // NCHUNK*256

typedef float f32x4 __attribute__((ext_vector_type(4)));
typedef unsigned int u32x2 __attribute__((ext_vector_type(2)));

// f32 -> bf16 (round-to-nearest-even), packed manually (deterministic).
__device__ __forceinline__ unsigned int f2bf(float x) {
    unsigned int u = __float_as_uint(x);
    return (u + 0x7fffu + ((u >> 16) & 1u)) >> 16;
}
// unpack 4 bf16 (u32x2) -> f32x4 fma with scalar v
__device__ __forceinline__ void bf4_fma(u32x2 d, float v, f32x4& acc) {
    acc.x += v * __uint_as_float(d.x << 16);
    acc.y += v * __uint_as_float(d.x & 0xffff0000u);
    acc.z += v * __uint_as_float(d.y << 16);
    acc.w += v * __uint_as_float(d.y & 0xffff0000u);
}
__device__ __forceinline__ f32x4 bf4_unpack(u32x2 d) {
    f32x4 r;
    r.x = __uint_as_float(d.x << 16);
    r.y = __uint_as_float(d.x & 0xffff0000u);
    r.z = __uint_as_float(d.y << 16);
    r.w = __uint_as_float(d.y & 0xffff0000u);
    return r;
}

// ---------------------------------------------------------------------------
// K1: FUSED. Blocks [0,NB): dual LDS histogram (count + weighted degree,
// 80 KB) + chunk partials. Blocks [NB, NB+157): gemm1 = x@W1^T -> BF16 table.
// Block NB+157: conv/fc weight fold.
__global__ __launch_bounds__(256) void fused_hist_gemm(const int* __restrict__ ei,
        const float* __restrict__ ew,
        const float* __restrict__ x, const float* __restrict__ W1,
        int* __restrict__ hist, float* __restrict__ dhist, int* __restrict__ pcs,
        ushort* __restrict__ outb,
        const float* __restrict__ conv_w, const float* __restrict__ conv_b,
        const float* __restrict__ fc_w, const float* __restrict__ fc_b,
        float* __restrict__ vbuf, float* __restrict__ c0) {
    __shared__ __align__(16) char smem[NPAD * 8];    // 80 KB union
    int t = threadIdx.x;
    int bid = blockIdx.x;
    if (bid < NB) {
        int* h = (int*)smem;                         // 40 KB counts
        float* hf = (float*)(smem + NPAD * 4);       // 40 KB weighted degree
        for (int i = t; i < 2 * NPAD; i += 256) ((int*)smem)[i] = 0;
        __syncthreads();
        int e0 = bid * EPB;
        for (int i = t; i < EPB; i += 256) {
            int e = e0 + i;
            int c = ei[N_EDGES + e];
            atomicAdd(&h[c], 1);                     // LDS atomics
            atomicAdd(&hf[c], ew[e]);
        }
        __syncthreads();
        for (int i = t; i < N_NODES; i += 256) {
            hist[bid * N_NODES + i] = h[i];
            dhist[bid * N_NODES + i] = hf[i];
        }
        int lane = t & 63, wave = t >> 6;
        for (int cch = wave; cch < NCHUNK; cch += 4) {
            int s = h[cch * 256 + lane] + h[cch * 256 + lane + 64]
                  + h[cch * 256 + lane + 128] + h[cch * 256 + lane + 192];
            #pragma unroll
            for (int off = 32; off > 0; off >>= 1) s += __shfl_down(s, off, 64);
            if (lane == 0) pcs[cch * NB + bid] = s;  // chunk-major layout
        }
        return;
    }
    if (bid == NB + (N_NODES + 63) / 64) {
        for (int i = t; i <= 384; i += 256) {
            if (i < 384) {
                float s = 0.0f;
                for (int o = 0; o < CH; ++o) s += fc_w[o] * conv_w[o * 384 + i];
                vbuf[i] = s;
            } else {
                float s = fc_b[0];
                for (int o = 0; o < CH; ++o) s += fc_w[o] * conv_b[o];
                *c0 = s;
            }
        }
        return;
    }
    // ---- gemm path: outb[m][o] = bf16( sum_k x[m][k] * W1[o][k] ) ----
    float (*As)[68]  = (float(*)[68])smem;
    float (*Ws)[132] = (float(*)[132])(smem + 32 * 68 * sizeof(float));
    int tx = t & 31;
    int ty = t >> 5;
    int row0 = (bid - NB) * 64;
    float acc[8][4] = {};
    for (int k0 = 0; k0 < 128; k0 += 32) {
        #pragma unroll
        for (int i = 0; i < 8; ++i) {
            int idx = t + i * 256;
            int r = idx >> 5, k = idx & 31;
            int gr = row0 + r;
            As[k][r] = (gr < N_NODES) ? x[gr * CH + k0 + k] : 0.0f;
        }
        #pragma unroll
        for (int i = 0; i < 16; ++i) {
            int idx = t + i * 256;
            int o = idx >> 5, k = idx & 31;
            Ws[k][o] = W1[o * CH + k0 + k];
        }
        __syncthreads();
        #pragma unroll
        for (int kk = 0; kk < 32; ++kk) {
            float a[8], w[4];
            #pragma unroll
            for (int j = 0; j < 8; ++j) a[j] = As[kk][ty * 8 + j];
            #pragma unroll
            for (int c = 0; c < 4; ++c) w[c] = Ws[kk][tx * 4 + c];
            #pragma unroll
            for (int j = 0; j < 8; ++j)
                #pragma unroll
                for (int c = 0; c < 4; ++c)
                    acc[j][c] += a[j] * w[c];
        }
        __syncthreads();
    }
    #pragma unroll
    for (int j = 0; j < 8; ++j) {
        int gr = row0 + ty * 8 + j;
        if (gr < N_NODES) {
            u32x2 p;
            p.x = f2bf(acc[j][0]) | (f2bf(acc[j][1]) << 16);
            p.y = f2bf(acc[j][2]) | (f2bf(acc[j][3]) << 16);
            *reinterpret_cast<u32x2*>(&outb[gr * CH + tx * 4]) = p;
        }
    }
}

// ---------------------------------------------------------------------------
// K2: per-node totals + dinv + global exclusive prefix + cursor conversion.
// (round-4 proven, verbatim)
__global__ __launch_bounds__(256) void bofs_kernel(int* __restrict__ hist,
        const float* __restrict__ dhist, const int* __restrict__ pcs,
        int* __restrict__ tot, int* __restrict__ offs, float* __restrict__ dinv) {
    __shared__ int wred[4];
    __shared__ int wsum[4];
    __shared__ int base_sh;
    int blk = blockIdx.x, t = threadIdx.x;
    int lane = t & 63, wave = t >> 6;
    int bsum = 0;
    for (int i = t; i < blk * NB; i += 256) bsum += pcs[i];
    #pragma unroll
    for (int off = 32; off > 0; off >>= 1) bsum += __shfl_down(bsum, off, 64);
    if (lane == 0) wred[wave] = bsum;
    __syncthreads();
    if (t == 0) base_sh = wred[0] + wred[1] + wred[2] + wred[3];
    int n = blk * 256 + t;
    int v = 0;
    if (n < N_NODES) {
        float dsum = 0.0f;
        #pragma unroll 8
        for (int b = 0; b < NB; ++b) {
            v += hist[b * N_NODES + n];
            dsum += dhist[b * N_NODES + n];
        }
        tot[n] = v;
        dinv[n] = rsqrtf(dsum + 1.0f);            // +1 = self-loop weight
    }
    int s = v;
    #pragma unroll
    for (int off = 1; off < 64; off <<= 1) {
        int u = __shfl_up(s, off, 64);
        if (lane >= off) s += u;
    }
    if (lane == 63) wsum[wave] = s;
    __syncthreads();
    int wbase = 0;
    for (int i = 0; i < wave; ++i) wbase += wsum[i];
    if (n < N_NODES) {
        int run = base_sh + wbase + s - v;        // global exclusive prefix
        offs[n] = run;
        for (int b = 0; b < NB; ++b) {
            int h = hist[b * N_NODES + n];
            hist[b * N_NODES + n] = run;          // column -> start cursor
            run += h;
        }
    }
}

// ---------------------------------------------------------------------------
// K3: scatter edges into CSR order via LDS cursors; records carry the fully
// NORMALIZED value dinv[r]*w*dinv[c].  (round-4 proven, verbatim)
__global__ __launch_bounds__(256) void scatter_kernel(const int* __restrict__ ei,
        const float* __restrict__ ew, const float* __restrict__ dinv,
        const int* __restrict__ bofs, int2* __restrict__ erec) {
    __shared__ int cur[N_NODES];                 // 40 KB
    __shared__ float di[N_NODES];                // 40 KB
    int b = blockIdx.x, t = threadIdx.x;
    for (int i = t; i < N_NODES; i += 256) {
        cur[i] = bofs[b * N_NODES + i];
        di[i] = dinv[i];
    }
    __syncthreads();
    int e0 = b * EPB;
    for (int i = t; i < EPB; i += 256) {
        int e = e0 + i;
        int r = ei[e];
        int c = ei[N_EDGES + e];
        float v = di[r] * ew[e] * di[c];
        int p = atomicAdd(&cur[c], 1);           // LDS atomic
        erec[p] = make_int2(r, __float_as_int(v));
    }
}

// ---------------------------------------------------------------------------
// 8-wide bf16-row gathers (dwordx2), all waits INTERNAL to one asm block
// (round-11 lesson: in-flight dests must never cross statement boundaries).
#define GATHER8B_ASM(F0,F1,F2,F3,F4,F5,F6,F7, P0,P1,P2,P3,P4,P5,P6,P7)       \
    asm volatile(                                                            \
        "global_load_dwordx2 %0, %8, off\n\t"                                \
        "global_load_dwordx2 %1, %9, off\n\t"                                \
        "global_load_dwordx2 %2, %10, off\n\t"                               \
        "global_load_dwordx2 %3, %11, off\n\t"                               \
        "global_load_dwordx2 %4, %12, off\n\t"                               \
        "global_load_dwordx2 %5, %13, off\n\t"                               \
        "global_load_dwordx2 %6, %14, off\n\t"                               \
        "global_load_dwordx2 %7, %15, off\n\t"                               \
        "s_waitcnt vmcnt(0)"                                                 \
        : "=&v"(F0), "=&v"(F1), "=&v"(F2), "=&v"(F3),                        \
          "=&v"(F4), "=&v"(F5), "=&v"(F6), "=&v"(F7)                         \
        : "v"(P0), "v"(P1), "v"(P2), "v"(P3),                                \
          "v"(P4), "v"(P5), "v"(P6), "v"(P7))

// Edge sweep over bf16 table xb (u32x2 = 4 bf16 channels per lane).
#define EDGE_SWEEP_BF() \
    int i = 0; \
    for (; i + 8 <= ns; i += 8) { \
        int2 r0 = lrec[g][i+0], r1 = lrec[g][i+1], r2 = lrec[g][i+2], r3 = lrec[g][i+3]; \
        int2 r4 = lrec[g][i+4], r5 = lrec[g][i+5], r6 = lrec[g][i+6], r7 = lrec[g][i+7]; \
        const u32x2 *p0 = xb + ((size_t)r0.x * 32 + l), *p1 = xb + ((size_t)r1.x * 32 + l); \
        const u32x2 *p2 = xb + ((size_t)r2.x * 32 + l), *p3 = xb + ((size_t)r3.x * 32 + l); \
        const u32x2 *p4 = xb + ((size_t)r4.x * 32 + l), *p5 = xb + ((size_t)r5.x * 32 + l); \
        const u32x2 *p6 = xb + ((size_t)r6.x * 32 + l), *p7 = xb + ((size_t)r7.x * 32 + l); \
        u32x2 f0, f1, f2, f3, f4, f5, f6, f7; \
        GATHER8B_ASM(f0, f1, f2, f3, f4, f5, f6, f7, p0, p1, p2, p3, p4, p5, p6, p7); \
        bf4_fma(f0, __int_as_float(r0.y), acc); \
        bf4_fma(f1, __int_as_float(r1.y), acc); \
        bf4_fma(f2, __int_as_float(r2.y), acc); \
        bf4_fma(f3, __int_as_float(r3.y), acc); \
        bf4_fma(f4, __int_as_float(r4.y), acc); \
        bf4_fma(f5, __int_as_float(r5.y), acc); \
        bf4_fma(f6, __int_as_float(r6.y), acc); \
        bf4_fma(f7, __int_as_float(r7.y), acc); \
    } \
    for (; i < num; ++i) { \
        int2 r = (i < ns) ? lrec[g][i] : erec[start + i]; \
        u32x2 dv = xb[(size_t)r.x * 32 + l]; \
        bf4_fma(dv, __int_as_float(r.y), acc); \
    }

// ---------------------------------------------------------------------------
// K4: FUSED agg1 + gemm2. bf16 gather table in, bf16 table out (for agg2).
__global__ __launch_bounds__(256) void agg_gemm_kernel(const u32x2* __restrict__ xb,
        const int2* __restrict__ erec, const int* __restrict__ offs,
        const int* __restrict__ cnt, const float* __restrict__ dinv,
        const float* __restrict__ bias, const float* __restrict__ W2,
        ushort* __restrict__ outb) {
    __shared__ float hs[8][128];                 // 4 KB relu'd h1 rows
    __shared__ int2 lrec[8][128];                // 8 KB staged records
    int l = threadIdx.x & 31;                    // channel quad
    int g = threadIdx.x >> 5;                    // node group 0..7
    int n = blockIdx.x * 8 + g;
    int start = offs[n];
    int num = cnt[n];
    int ns = num <= 128 ? num : 128;             // deg>128: astronomically rare
    for (int i = l; i < ns; i += 32)             // coalesced staging
        lrec[g][i] = erec[start + i];            // same-wave producer/consumer
    float d = dinv[n];
    float dd = d * d;
    f32x4 self = bf4_unpack(xb[(size_t)n * 32 + l]);
    f32x4 acc = dd * self;
    EDGE_SWEEP_BF()
    const f32x4 bb = ((const f32x4*)bias)[l];
    f32x4 h;
    h.x = fmaxf(acc.x + bb.x, 0.0f);
    h.y = fmaxf(acc.y + bb.y, 0.0f);
    h.z = fmaxf(acc.z + bb.z, 0.0f);
    h.w = fmaxf(acc.w + bb.w, 0.0f);
    *reinterpret_cast<f32x4*>(&hs[g][4 * l]) = h;
    __syncthreads();
    // ---- mini-GEMM (fp32): thread = (channel o, row-group rg of 4 rows) ----
    int o = threadIdx.x & 127;
    int rg = threadIdx.x >> 7;                   // 0: rows 0-3, 1: rows 4-7
    const float4* w4p = reinterpret_cast<const float4*>(&W2[o * CH]);
    const float4* h0p = reinterpret_cast<const float4*>(&hs[rg * 4 + 0][0]);
    const float4* h1p = reinterpret_cast<const float4*>(&hs[rg * 4 + 1][0]);
    const float4* h2p = reinterpret_cast<const float4*>(&hs[rg * 4 + 2][0]);
    const float4* h3p = reinterpret_cast<const float4*>(&hs[rg * 4 + 3][0]);
    float a0 = 0.0f, a1 = 0.0f, a2 = 0.0f, a3 = 0.0f;
    #pragma unroll 8
    for (int k4 = 0; k4 < 32; ++k4) {
        float4 w = w4p[k4];                      // L2-hot W2 row
        float4 h0 = h0p[k4], h1 = h1p[k4], h2 = h2p[k4], h3 = h3p[k4];
        a0 += w.x * h0.x + w.y * h0.y + w.z * h0.z + w.w * h0.w;
        a1 += w.x * h1.x + w.y * h1.y + w.z * h1.z + w.w * h1.w;
        a2 += w.x * h2.x + w.y * h2.y + w.z * h2.z + w.w * h2.w;
        a3 += w.x * h3.x + w.y * h3.y + w.z * h3.z + w.w * h3.w;
    }
    int nb2 = blockIdx.x * 8 + rg * 4;
    outb[(nb2 + 0) * CH + o] = (ushort)f2bf(a0); // 256B/row coalesced
    outb[(nb2 + 1) * CH + o] = (ushort)f2bf(a1);
    outb[(nb2 + 2) * CH + o] = (ushort)f2bf(a2);
    outb[(nb2 + 3) * CH + o] = (ushort)f2bf(a3);
}

// ---------------------------------------------------------------------------
// K5: agg layer 2 — bf16 gather table in, fp32 out (convfc input).
__global__ __launch_bounds__(256) void agg_kernel(const u32x2* __restrict__ xb,
        const int2* __restrict__ erec, const int* __restrict__ offs,
        const int* __restrict__ cnt, const float* __restrict__ dinv,
        const float* __restrict__ bias, f32x4* __restrict__ out4) {
    __shared__ int2 lrec[8][128];                // 8 KB staged records
    int l = threadIdx.x & 31;
    int g = threadIdx.x >> 5;
    int n = blockIdx.x * 8 + g;
    int start = offs[n];
    int num = cnt[n];
    int ns = num <= 128 ? num : 128;
    for (int i = l; i < ns; i += 32)
        lrec[g][i] = erec[start + i];
    float d = dinv[n];
    float dd = d * d;
    f32x4 self = bf4_unpack(xb[(size_t)n * 32 + l]);
    f32x4 acc = dd * self;
    EDGE_SWEEP_BF()
    const f32x4 bb = ((const f32x4*)bias)[l];
    f32x4 h;
    h.x = fmaxf(acc.x + bb.x, 0.0f);
    h.y = fmaxf(acc.y + bb.y, 0.0f);
    h.z = fmaxf(acc.z + bb.z, 0.0f);
    h.w = fmaxf(acc.w + bb.w, 0.0f);
    out4[(size_t)n * 32 + l] = h;
}

// ---------------------------------------------------------------------------
// K6: fused temporal conv + fc: one wave per node, lane handles ch l and l+64.
__global__ __launch_bounds__(256) void convfc_kernel(const float* __restrict__ h,
        const float* __restrict__ v, const float* __restrict__ c0,
        float* __restrict__ out, int N) {
    int n = blockIdx.x * 4 + (threadIdx.x >> 6);
    int l = threadIdx.x & 63;
    if (n >= N) return;
    const float* hn = h + n * CH;
    float v0a = v[l * 3 + 0],        v1a = v[l * 3 + 1],        v2a = v[l * 3 + 2];
    float v0b = v[(l + 64) * 3 + 0], v1b = v[(l + 64) * 3 + 1], v2b = v[(l + 64) * 3 + 2];
    float p = hn[l] * v1a + hn[l + 64] * v1b;
    if (n > 0)     p += hn[l - CH] * v0a + hn[l + 64 - CH] * v0b;
    if (n < N - 1) p += hn[l + CH] * v2a + hn[l + 64 + CH] * v2b;
    #pragma unroll
    for (int off = 32; off > 0; off >>= 1) p += __shfl_down(p, off, 64);
    if (l == 0) out[n] = p + *c0;
}

// ---------------------------------------------------------------------------
extern "C" void kernel_launch(void* const* d_in, const int* in_sizes, int n_in,
                              void* d_out, int out_size, void* d_ws, size_t ws_size,
                              hipStream_t stream) {
    const float* x       = (const float*)d_in[0];
    const int*   ei      = (const int*)d_in[1];
    const float* ew      = (const float*)d_in[2];
    const float* W1      = (const float*)d_in[3];
    const float* b1      = (const float*)d_in[4];
    const float* W2      = (const float*)d_in[5];
    const float* b2      = (const float*)d_in[6];
    const float* conv_w  = (const float*)d_in[7];
    const float* conv_b  = (const float*)d_in[8];
    const float* fc_w    = (const float*)d_in[9];
    const float* fc_b    = (const float*)d_in[10];
    float* out = (float*)d_out;

    ushort* xb1   = (ushort*)d_ws;                  // 10,000x128 bf16 (xw1 table)
    ushort* xb2   = xb1 + N_NODES * CH;             // 10,000x128 bf16 (xw2 table)
    float* bufC   = (float*)(xb2 + N_NODES * CH);   // 1,280,000 f (h2, fp32)
    int2*  erec   = (int2*)(bufC + N_NODES * CH);   // 640,000 x 8B
    int*   hist   = (int*)(erec + N_EDGES);         // NB*10,000 i
    float* dhist  = (float*)(hist + NB * N_NODES);  // NB*10,000 f
    int*   pcs    = (int*)(dhist + NB * N_NODES);   // NCHUNK*NB i
    int*   tot    = pcs + NCHUNK * NB;              // 10,000 i
    int*   offs   = tot + N_NODES;                  // 10,000 i
    float* dinv   = (float*)(offs + N_NODES);       // 10,000 f
    float* vbuf   = dinv + N_NODES;                 // 384 f
    float* c0     = vbuf + 384;                     // 1 f

    const int gemm_grid = (N_NODES + 63) / 64;      // 157

    // K1: dual-hist (64) + gemm1->bf16 (157) + weight-fold (1)
    fused_hist_gemm<<<NB + gemm_grid + 1, 256, 0, stream>>>(ei, ew, x, W1,
            hist, dhist, pcs, xb1, conv_w, conv_b, fc_w, fc_b, vbuf, c0);
    // K2: totals + dinv + prefix + cursor conversion
    bofs_kernel<<<NCHUNK, 256, 0, stream>>>(hist, dhist, pcs, tot, offs, dinv);
    // K3: normalized CSR scatter
    scatter_kernel<<<NB, 256, 0, stream>>>(ei, ew, dinv, hist, erec);
    // K4: agg1 + gemm2 fused (bf16 gathers): xb1 -> xb2
    agg_gemm_kernel<<<N_NODES / 8, 256, 0, stream>>>((const u32x2*)xb1, erec, offs,
            tot, dinv, b1, W2, xb2);
    // K5: agg layer 2 (bf16 gathers): xb2 -> bufC (fp32)
    agg_kernel<<<N_NODES / 8, 256, 0, stream>>>((const u32x2*)xb2, erec, offs, tot,
                                                dinv, b2, (f32x4*)bufC);
    // K6: fused temporal conv + fc
    convfc_kernel<<<(N_NODES + 3) / 4, 256, 0, stream>>>(bufC, vbuf, c0, out, N_NODES);
}

// Round 14
// 189.646 us; speedup vs baseline: 1.0951x; 1.0058x over previous
//
#include <hip/hip_runtime.h>
#include <hip/hip_bf16.h>

#define N_NODES 10000
#define N_EDGES 640000
#define CH 128
#define NB 64                // histogram/scatter blocks
#define EPB (N_EDGES / NB)   // 10000 edges per block
#define NCHUNK 40            // ceil(N_NODES/256) scan chunks
#define NPAD 10240           // NCHUNK*256

typedef float f32x4 __attribute__((ext_vector_type(4)));
typedef unsigned int u32x2 __attribute__((ext_vector_type(2)));

// f32 -> bf16 (round-to-nearest-even), packed manually (deterministic).
__device__ __forceinline__ unsigned int f2bf(float x) {
    unsigned int u = __float_as_uint(x);
    return (u + 0x7fffu + ((u >> 16) & 1u)) >> 16;
}
// unpack 4 bf16 (u32x2) -> f32x4 fma with scalar v
__device__ __forceinline__ void bf4_fma(u32x2 d, float v, f32x4& acc) {
    acc.x += v * __uint_as_float(d.x << 16);
    acc.y += v * __uint_as_float(d.x & 0xffff0000u);
    acc.z += v * __uint_as_float(d.y << 16);
    acc.w += v * __uint_as_float(d.y & 0xffff0000u);
}
__device__ __forceinline__ f32x4 bf4_unpack(u32x2 d) {
    f32x4 r;
    r.x = __uint_as_float(d.x << 16);
    r.y = __uint_as_float(d.x & 0xffff0000u);
    r.z = __uint_as_float(d.y << 16);
    r.w = __uint_as_float(d.y & 0xffff0000u);
    return r;
}
// 4B edge record: high 16 = bf16(normalized val), low 16 = src node id.
__device__ __forceinline__ float rec_val(unsigned int rec) {
    return __uint_as_float(rec & 0xffff0000u);
}
__device__ __forceinline__ unsigned int rec_src(unsigned int rec) {
    return rec & 0xffffu;
}

// ---------------------------------------------------------------------------
// K1: FUSED. Blocks [0,NB): dual LDS histogram (count + weighted degree,
// 80 KB) + chunk partials. Blocks [NB, NB+157): gemm1 = x@W1^T -> BF16 table.
// Block NB+157: conv/fc weight fold.  (round-13 proven, verbatim)
__global__ __launch_bounds__(256) void fused_hist_gemm(const int* __restrict__ ei,
        const float* __restrict__ ew,
        const float* __restrict__ x, const float* __restrict__ W1,
        int* __restrict__ hist, float* __restrict__ dhist, int* __restrict__ pcs,
        ushort* __restrict__ outb,
        const float* __restrict__ conv_w, const float* __restrict__ conv_b,
        const float* __restrict__ fc_w, const float* __restrict__ fc_b,
        float* __restrict__ vbuf, float* __restrict__ c0) {
    __shared__ __align__(16) char smem[NPAD * 8];    // 80 KB union
    int t = threadIdx.x;
    int bid = blockIdx.x;
    if (bid < NB) {
        int* h = (int*)smem;                         // 40 KB counts
        float* hf = (float*)(smem + NPAD * 4);       // 40 KB weighted degree
        for (int i = t; i < 2 * NPAD; i += 256) ((int*)smem)[i] = 0;
        __syncthreads();
        int e0 = bid * EPB;
        for (int i = t; i < EPB; i += 256) {
            int e = e0 + i;
            int c = ei[N_EDGES + e];
            atomicAdd(&h[c], 1);                     // LDS atomics
            atomicAdd(&hf[c], ew[e]);
        }
        __syncthreads();
        for (int i = t; i < N_NODES; i += 256) {
            hist[bid * N_NODES + i] = h[i];
            dhist[bid * N_NODES + i] = hf[i];
        }
        int lane = t & 63, wave = t >> 6;
        for (int cch = wave; cch < NCHUNK; cch += 4) {
            int s = h[cch * 256 + lane] + h[cch * 256 + lane + 64]
                  + h[cch * 256 + lane + 128] + h[cch * 256 + lane + 192];
            #pragma unroll
            for (int off = 32; off > 0; off >>= 1) s += __shfl_down(s, off, 64);
            if (lane == 0) pcs[cch * NB + bid] = s;  // chunk-major layout
        }
        return;
    }
    if (bid == NB + (N_NODES + 63) / 64) {
        for (int i = t; i <= 384; i += 256) {
            if (i < 384) {
                float s = 0.0f;
                for (int o = 0; o < CH; ++o) s += fc_w[o] * conv_w[o * 384 + i];
                vbuf[i] = s;
            } else {
                float s = fc_b[0];
                for (int o = 0; o < CH; ++o) s += fc_w[o] * conv_b[o];
                *c0 = s;
            }
        }
        return;
    }
    // ---- gemm path: outb[m][o] = bf16( sum_k x[m][k] * W1[o][k] ) ----
    float (*As)[68]  = (float(*)[68])smem;
    float (*Ws)[132] = (float(*)[132])(smem + 32 * 68 * sizeof(float));
    int tx = t & 31;
    int ty = t >> 5;
    int row0 = (bid - NB) * 64;
    float acc[8][4] = {};
    for (int k0 = 0; k0 < 128; k0 += 32) {
        #pragma unroll
        for (int i = 0; i < 8; ++i) {
            int idx = t + i * 256;
            int r = idx >> 5, k = idx & 31;
            int gr = row0 + r;
            As[k][r] = (gr < N_NODES) ? x[gr * CH + k0 + k] : 0.0f;
        }
        #pragma unroll
        for (int i = 0; i < 16; ++i) {
            int idx = t + i * 256;
            int o = idx >> 5, k = idx & 31;
            Ws[k][o] = W1[o * CH + k0 + k];
        }
        __syncthreads();
        #pragma unroll
        for (int kk = 0; kk < 32; ++kk) {
            float a[8], w[4];
            #pragma unroll
            for (int j = 0; j < 8; ++j) a[j] = As[kk][ty * 8 + j];
            #pragma unroll
            for (int c = 0; c < 4; ++c) w[c] = Ws[kk][tx * 4 + c];
            #pragma unroll
            for (int j = 0; j < 8; ++j)
                #pragma unroll
                for (int c = 0; c < 4; ++c)
                    acc[j][c] += a[j] * w[c];
        }
        __syncthreads();
    }
    #pragma unroll
    for (int j = 0; j < 8; ++j) {
        int gr = row0 + ty * 8 + j;
        if (gr < N_NODES) {
            u32x2 p;
            p.x = f2bf(acc[j][0]) | (f2bf(acc[j][1]) << 16);
            p.y = f2bf(acc[j][2]) | (f2bf(acc[j][3]) << 16);
            *reinterpret_cast<u32x2*>(&outb[gr * CH + tx * 4]) = p;
        }
    }
}

// ---------------------------------------------------------------------------
// K2: per-node totals + dinv + global exclusive prefix + cursor conversion.
// (round-4 proven, verbatim)
__global__ __launch_bounds__(256) void bofs_kernel(int* __restrict__ hist,
        const float* __restrict__ dhist, const int* __restrict__ pcs,
        int* __restrict__ tot, int* __restrict__ offs, float* __restrict__ dinv) {
    __shared__ int wred[4];
    __shared__ int wsum[4];
    __shared__ int base_sh;
    int blk = blockIdx.x, t = threadIdx.x;
    int lane = t & 63, wave = t >> 6;
    int bsum = 0;
    for (int i = t; i < blk * NB; i += 256) bsum += pcs[i];
    #pragma unroll
    for (int off = 32; off > 0; off >>= 1) bsum += __shfl_down(bsum, off, 64);
    if (lane == 0) wred[wave] = bsum;
    __syncthreads();
    if (t == 0) base_sh = wred[0] + wred[1] + wred[2] + wred[3];
    int n = blk * 256 + t;
    int v = 0;
    if (n < N_NODES) {
        float dsum = 0.0f;
        #pragma unroll 8
        for (int b = 0; b < NB; ++b) {
            v += hist[b * N_NODES + n];
            dsum += dhist[b * N_NODES + n];
        }
        tot[n] = v;
        dinv[n] = rsqrtf(dsum + 1.0f);            // +1 = self-loop weight
    }
    int s = v;
    #pragma unroll
    for (int off = 1; off < 64; off <<= 1) {
        int u = __shfl_up(s, off, 64);
        if (lane >= off) s += u;
    }
    if (lane == 63) wsum[wave] = s;
    __syncthreads();
    int wbase = 0;
    for (int i = 0; i < wave; ++i) wbase += wsum[i];
    if (n < N_NODES) {
        int run = base_sh + wbase + s - v;        // global exclusive prefix
        offs[n] = run;
        for (int b = 0; b < NB; ++b) {
            int h = hist[b * N_NODES + n];
            hist[b * N_NODES + n] = run;          // column -> start cursor
            run += h;
        }
    }
}

// ---------------------------------------------------------------------------
// K3: scatter edges into CSR order via LDS cursors; 4 B records:
// (bf16(dinv[r]*w*dinv[c]) << 16) | src.  Write traffic halves vs int2.
__global__ __launch_bounds__(256) void scatter_kernel(const int* __restrict__ ei,
        const float* __restrict__ ew, const float* __restrict__ dinv,
        const int* __restrict__ bofs, unsigned int* __restrict__ erec) {
    __shared__ int cur[N_NODES];                 // 40 KB
    __shared__ float di[N_NODES];                // 40 KB
    int b = blockIdx.x, t = threadIdx.x;
    for (int i = t; i < N_NODES; i += 256) {
        cur[i] = bofs[b * N_NODES + i];
        di[i] = dinv[i];
    }
    __syncthreads();
    int e0 = b * EPB;
    for (int i = t; i < EPB; i += 256) {
        int e = e0 + i;
        int r = ei[e];
        int c = ei[N_EDGES + e];
        float v = di[r] * ew[e] * di[c];
        int p = atomicAdd(&cur[c], 1);           // LDS atomic
        erec[p] = (f2bf(v) << 16) | (unsigned int)r;
    }
}

// ---------------------------------------------------------------------------
// 8-wide bf16-row gathers (dwordx2), all waits INTERNAL to one asm block
// (round-11 lesson: in-flight dests must never cross statement boundaries).
#define GATHER8B_ASM(F0,F1,F2,F3,F4,F5,F6,F7, P0,P1,P2,P3,P4,P5,P6,P7)       \
    asm volatile(                                                            \
        "global_load_dwordx2 %0, %8, off\n\t"                                \
        "global_load_dwordx2 %1, %9, off\n\t"                                \
        "global_load_dwordx2 %2, %10, off\n\t"                               \
        "global_load_dwordx2 %3, %11, off\n\t"                               \
        "global_load_dwordx2 %4, %12, off\n\t"                               \
        "global_load_dwordx2 %5, %13, off\n\t"                               \
        "global_load_dwordx2 %6, %14, off\n\t"                               \
        "global_load_dwordx2 %7, %15, off\n\t"                               \
        "s_waitcnt vmcnt(0)"                                                 \
        : "=&v"(F0), "=&v"(F1), "=&v"(F2), "=&v"(F3),                        \
          "=&v"(F4), "=&v"(F5), "=&v"(F6), "=&v"(F7)                         \
        : "v"(P0), "v"(P1), "v"(P2), "v"(P3),                                \
          "v"(P4), "v"(P5), "v"(P6), "v"(P7))

// Edge sweep over bf16 table xb; 4 B records in lrec.
#define EDGE_SWEEP_BF() \
    int i = 0; \
    for (; i + 8 <= ns; i += 8) { \
        unsigned int r0 = lrec[g][i+0], r1 = lrec[g][i+1]; \
        unsigned int r2 = lrec[g][i+2], r3 = lrec[g][i+3]; \
        unsigned int r4 = lrec[g][i+4], r5 = lrec[g][i+5]; \
        unsigned int r6 = lrec[g][i+6], r7 = lrec[g][i+7]; \
        const u32x2 *p0 = xb + ((size_t)rec_src(r0) * 32 + l); \
        const u32x2 *p1 = xb + ((size_t)rec_src(r1) * 32 + l); \
        const u32x2 *p2 = xb + ((size_t)rec_src(r2) * 32 + l); \
        const u32x2 *p3 = xb + ((size_t)rec_src(r3) * 32 + l); \
        const u32x2 *p4 = xb + ((size_t)rec_src(r4) * 32 + l); \
        const u32x2 *p5 = xb + ((size_t)rec_src(r5) * 32 + l); \
        const u32x2 *p6 = xb + ((size_t)rec_src(r6) * 32 + l); \
        const u32x2 *p7 = xb + ((size_t)rec_src(r7) * 32 + l); \
        u32x2 f0, f1, f2, f3, f4, f5, f6, f7; \
        GATHER8B_ASM(f0, f1, f2, f3, f4, f5, f6, f7, p0, p1, p2, p3, p4, p5, p6, p7); \
        bf4_fma(f0, rec_val(r0), acc); \
        bf4_fma(f1, rec_val(r1), acc); \
        bf4_fma(f2, rec_val(r2), acc); \
        bf4_fma(f3, rec_val(r3), acc); \
        bf4_fma(f4, rec_val(r4), acc); \
        bf4_fma(f5, rec_val(r5), acc); \
        bf4_fma(f6, rec_val(r6), acc); \
        bf4_fma(f7, rec_val(r7), acc); \
    } \
    for (; i < num; ++i) { \
        unsigned int r = (i < ns) ? lrec[g][i] : erec[start + i]; \
        u32x2 dv = xb[(size_t)rec_src(r) * 32 + l]; \
        bf4_fma(dv, rec_val(r), acc); \
    }

// ---------------------------------------------------------------------------
// K4: FUSED agg1 + gemm2. bf16 gather table in, bf16 table out (for agg2).
__global__ __launch_bounds__(256) void agg_gemm_kernel(const u32x2* __restrict__ xb,
        const unsigned int* __restrict__ erec, const int* __restrict__ offs,
        const int* __restrict__ cnt, const float* __restrict__ dinv,
        const float* __restrict__ bias, const float* __restrict__ W2,
        ushort* __restrict__ outb) {
    __shared__ float hs[8][128];                 // 4 KB relu'd h1 rows
    __shared__ unsigned int lrec[8][128];        // 4 KB staged 4B records
    int l = threadIdx.x & 31;                    // channel quad
    int g = threadIdx.x >> 5;                    // node group 0..7
    int n = blockIdx.x * 8 + g;
    int start = offs[n];
    int num = cnt[n];
    int ns = num <= 128 ? num : 128;             // deg>128: astronomically rare
    for (int i = l; i < ns; i += 32)             // coalesced staging
        lrec[g][i] = erec[start + i];            // same-wave producer/consumer
    float d = dinv[n];
    float dd = d * d;
    f32x4 self = bf4_unpack(xb[(size_t)n * 32 + l]);
    f32x4 acc = dd * self;
    EDGE_SWEEP_BF()
    const f32x4 bb = ((const f32x4*)bias)[l];
    f32x4 h;
    h.x = fmaxf(acc.x + bb.x, 0.0f);
    h.y = fmaxf(acc.y + bb.y, 0.0f);
    h.z = fmaxf(acc.z + bb.z, 0.0f);
    h.w = fmaxf(acc.w + bb.w, 0.0f);
    *reinterpret_cast<f32x4*>(&hs[g][4 * l]) = h;
    __syncthreads();
    // ---- mini-GEMM (fp32): thread = (channel o, row-group rg of 4 rows) ----
    int o = threadIdx.x & 127;
    int rg = threadIdx.x >> 7;                   // 0: rows 0-3, 1: rows 4-7
    const float4* w4p = reinterpret_cast<const float4*>(&W2[o * CH]);
    const float4* h0p = reinterpret_cast<const float4*>(&hs[rg * 4 + 0][0]);
    const float4* h1p = reinterpret_cast<const float4*>(&hs[rg * 4 + 1][0]);
    const float4* h2p = reinterpret_cast<const float4*>(&hs[rg * 4 + 2][0]);
    const float4* h3p = reinterpret_cast<const float4*>(&hs[rg * 4 + 3][0]);
    float a0 = 0.0f, a1 = 0.0f, a2 = 0.0f, a3 = 0.0f;
    #pragma unroll 8
    for (int k4 = 0; k4 < 32; ++k4) {
        float4 w = w4p[k4];                      // L2-hot W2 row
        float4 h0 = h0p[k4], h1 = h1p[k4], h2 = h2p[k4], h3 = h3p[k4];
        a0 += w.x * h0.x + w.y * h0.y + w.z * h0.z + w.w * h0.w;
        a1 += w.x * h1.x + w.y * h1.y + w.z * h1.z + w.w * h1.w;
        a2 += w.x * h2.x + w.y * h2.y + w.z * h2.z + w.w * h2.w;
        a3 += w.x * h3.x + w.y * h3.y + w.z * h3.z + w.w * h3.w;
    }
    int nb2 = blockIdx.x * 8 + rg * 4;
    outb[(nb2 + 0) * CH + o] = (ushort)f2bf(a0); // 256B/row coalesced
    outb[(nb2 + 1) * CH + o] = (ushort)f2bf(a1);
    outb[(nb2 + 2) * CH + o] = (ushort)f2bf(a2);
    outb[(nb2 + 3) * CH + o] = (ushort)f2bf(a3);
}

// ---------------------------------------------------------------------------
// K5: agg layer 2 — bf16 gather table in, BF16 packed out (convfc input).
__global__ __launch_bounds__(256) void agg_kernel(const u32x2* __restrict__ xb,
        const unsigned int* __restrict__ erec, const int* __restrict__ offs,
        const int* __restrict__ cnt, const float* __restrict__ dinv,
        const float* __restrict__ bias, u32x2* __restrict__ outb2) {
    __shared__ unsigned int lrec[8][128];        // 4 KB staged 4B records
    int l = threadIdx.x & 31;
    int g = threadIdx.x >> 5;
    int n = blockIdx.x * 8 + g;
    int start = offs[n];
    int num = cnt[n];
    int ns = num <= 128 ? num : 128;
    for (int i = l; i < ns; i += 32)
        lrec[g][i] = erec[start + i];
    float d = dinv[n];
    float dd = d * d;
    f32x4 self = bf4_unpack(xb[(size_t)n * 32 + l]);
    f32x4 acc = dd * self;
    EDGE_SWEEP_BF()
    const f32x4 bb = ((const f32x4*)bias)[l];
    float h0 = fmaxf(acc.x + bb.x, 0.0f);
    float h1 = fmaxf(acc.y + bb.y, 0.0f);
    float h2 = fmaxf(acc.z + bb.z, 0.0f);
    float h3 = fmaxf(acc.w + bb.w, 0.0f);
    u32x2 p;
    p.x = f2bf(h0) | (f2bf(h1) << 16);
    p.y = f2bf(h2) | (f2bf(h3) << 16);
    outb2[(size_t)n * 32 + l] = p;               // bf16 h2 table
}

// ---------------------------------------------------------------------------
// K6: fused temporal conv + fc over bf16 h2. One wave per node; lane l
// handles adjacent channels (2l, 2l+1) -> one u32 load per row.
__global__ __launch_bounds__(256) void convfc_kernel(const unsigned int* __restrict__ hb,
        const float* __restrict__ v, const float* __restrict__ c0,
        float* __restrict__ out, int N) {
    int n = blockIdx.x * 4 + (threadIdx.x >> 6);
    int l = threadIdx.x & 63;
    if (n >= N) return;
    const unsigned int* hn = hb + n * (CH / 2);  // u32 = 2 bf16 channels
    int ca = 2 * l, cb = 2 * l + 1;
    float v0a = v[ca * 3 + 0], v1a = v[ca * 3 + 1], v2a = v[ca * 3 + 2];
    float v0b = v[cb * 3 + 0], v1b = v[cb * 3 + 1], v2b = v[cb * 3 + 2];
    unsigned int m = hn[l];
    float p = __uint_as_float(m << 16) * v1a
            + __uint_as_float(m & 0xffff0000u) * v1b;
    if (n > 0) {
        unsigned int q = hn[l - CH / 2];
        p += __uint_as_float(q << 16) * v0a
           + __uint_as_float(q & 0xffff0000u) * v0b;
    }
    if (n < N - 1) {
        unsigned int q = hn[l + CH / 2];
        p += __uint_as_float(q << 16) * v2a
           + __uint_as_float(q & 0xffff0000u) * v2b;
    }
    #pragma unroll
    for (int off = 32; off > 0; off >>= 1) p += __shfl_down(p, off, 64);
    if (l == 0) out[n] = p + *c0;
}

// ---------------------------------------------------------------------------
extern "C" void kernel_launch(void* const* d_in, const int* in_sizes, int n_in,
                              void* d_out, int out_size, void* d_ws, size_t ws_size,
                              hipStream_t stream) {
    const float* x       = (const float*)d_in[0];
    const int*   ei      = (const int*)d_in[1];
    const float* ew      = (const float*)d_in[2];
    const float* W1      = (const float*)d_in[3];
    const float* b1      = (const float*)d_in[4];
    const float* W2      = (const float*)d_in[5];
    const float* b2      = (const float*)d_in[6];
    const float* conv_w  = (const float*)d_in[7];
    const float* conv_b  = (const float*)d_in[8];
    const float* fc_w    = (const float*)d_in[9];
    const float* fc_b    = (const float*)d_in[10];
    float* out = (float*)d_out;

    ushort* xb1   = (ushort*)d_ws;                  // 10,000x128 bf16 (xw1 table)
    ushort* xb2   = xb1 + N_NODES * CH;             // 10,000x128 bf16 (xw2 table)
    ushort* hb    = xb2 + N_NODES * CH;             // 10,000x128 bf16 (h2 table)
    unsigned int* erec = (unsigned int*)(hb + N_NODES * CH); // 640,000 x 4B
    int*   hist   = (int*)(erec + N_EDGES);         // NB*10,000 i
    float* dhist  = (float*)(hist + NB * N_NODES);  // NB*10,000 f
    int*   pcs    = (int*)(dhist + NB * N_NODES);   // NCHUNK*NB i
    int*   tot    = pcs + NCHUNK * NB;              // 10,000 i
    int*   offs   = tot + N_NODES;                  // 10,000 i
    float* dinv   = (float*)(offs + N_NODES);       // 10,000 f
    float* vbuf   = dinv + N_NODES;                 // 384 f
    float* c0     = vbuf + 384;                     // 1 f

    const int gemm_grid = (N_NODES + 63) / 64;      // 157

    // K1: dual-hist (64) + gemm1->bf16 (157) + weight-fold (1)
    fused_hist_gemm<<<NB + gemm_grid + 1, 256, 0, stream>>>(ei, ew, x, W1,
            hist, dhist, pcs, xb1, conv_w, conv_b, fc_w, fc_b, vbuf, c0);
    // K2: totals + dinv + prefix + cursor conversion
    bofs_kernel<<<NCHUNK, 256, 0, stream>>>(hist, dhist, pcs, tot, offs, dinv);
    // K3: normalized CSR scatter (4B records)
    scatter_kernel<<<NB, 256, 0, stream>>>(ei, ew, dinv, hist, erec);
    // K4: agg1 + gemm2 fused (bf16 gathers): xb1 -> xb2
    agg_gemm_kernel<<<N_NODES / 8, 256, 0, stream>>>((const u32x2*)xb1, erec, offs,
            tot, dinv, b1, W2, xb2);
    // K5: agg layer 2 (bf16 gathers): xb2 -> hb (bf16)
    agg_kernel<<<N_NODES / 8, 256, 0, stream>>>((const u32x2*)xb2, erec, offs, tot,
                                                dinv, b2, (u32x2*)hb);
    // K6: fused temporal conv + fc (bf16 input)
    convfc_kernel<<<(N_NODES + 3) / 4, 256, 0, stream>>>((const unsigned int*)hb,
                                                         vbuf, c0, out, N_NODES);
}